// Round 1
// baseline (109.952 us; speedup 1.0000x reference)
//
#include <hip/hip_runtime.h>

// AdaptiveVoxelization: two independent streaming kernels.
//  Output layout in d_out (float32, concatenated in reference return order):
//   [0, 12M)        coors  [N,3] in zyx order, -1 for out-of-range (as floats)
//   [12M, 15M)      centers [3, R^3] adaptive voxel centers
//   [15M, 16M)      center_mask [R^3] as 0.0/1.0
//
// Numerics: all float ops use __f*_rn intrinsics to match JAX/XLA f32
// (no fma contraction, no reciprocal-mul for division) — validity-mask
// flips at voxel boundaries would cost ~2000 absmax, so bitwise matching
// is required, not just "close".

#define RES 100
#define R3 (RES * RES * RES)

__global__ __launch_bounds__(256) void voxelize_kernel(
    const float4* __restrict__ pts, float* __restrict__ coors, int n) {
  int i = blockIdx.x * blockDim.x + threadIdx.x;
  if (i >= n) return;
  float4 p = pts[i];
  // c = floor((p - cmin) / vs), f32 IEEE ops exactly as XLA emits them
  float c0 = floorf(__fdiv_rn(__fsub_rn(p.x, -50.0f), 0.1f));
  float c1 = floorf(__fdiv_rn(__fsub_rn(p.y, -50.0f), 0.1f));
  float c2 = floorf(__fdiv_rn(__fsub_rn(p.z, -1.0f), 0.2f));
  // grid = round((pcr_hi - pcr_lo)/vs) in f32 = (2000, 1000, 20) exactly
  bool valid = (c0 >= 0.0f) && (c0 < 2000.0f) &&
               (c1 >= 0.0f) && (c1 < 1000.0f) &&
               (c2 >= 0.0f) && (c2 < 20.0f);
  float o0 = valid ? c2 : -1.0f;   // zyx order
  float o1 = valid ? c1 : -1.0f;
  float o2 = valid ? c0 : -1.0f;
  size_t b = (size_t)3 * i;
  coors[b]     = o0;
  coors[b + 1] = o1;
  coors[b + 2] = o2;
}

// JAX linspace(start, stop, RES, endpoint=True):
//   div = RES-1; t_k = k/div (f32); out_k = start*(1-t_k) + stop*t_k for k<div;
//   out[div] = stop exactly (endpoint concatenation).
__device__ __forceinline__ float lin_val(float start, float stop, int k) {
  if (k == RES - 1) return stop;
  float t = __fdiv_rn((float)k, (float)(RES - 1));
  return __fadd_rn(__fmul_rn(start, __fsub_rn(1.0f, t)),
                   __fmul_rn(stop, t));
}

__global__ __launch_bounds__(256) void centers_kernel(
    float* __restrict__ centers, float* __restrict__ mask) {
  int j = blockIdx.x * blockDim.x + threadIdx.x;
  if (j >= R3) return;
  // meshgrid 'ij' ravel: flat = i0*R^2 + i1*R + i2
  int i0 = j / (RES * RES);
  int rem = j - i0 * (RES * RES);
  int i1 = rem / RES;
  int i2 = rem - i1 * RES;
  float c0 = lin_val(-50.0f, 150.0f, i0);
  float c1 = lin_val(-50.0f, 50.0f, i1);
  float c2 = lin_val(-1.0f, 3.0f, i2);
  // norms = sqrt((c0^2 + c1^2) + c2^2), f32
  float s = __fadd_rn(__fadd_rn(__fmul_rn(c0, c0), __fmul_rn(c1, c1)),
                      __fmul_rn(c2, c2));
  float nrm = __fsqrt_rn(s);
  // norm_c = max|norms| = norm at corner (150, +-50, 3): 150^2+50^2+3^2 = 25009
  // (exact integer in f32; endpoint values are exact, so no interior value
  //  can exceed it even with rounding)
  float nc = __fsqrt_rn(25009.0f);
  // quadratic: sf = norms^2 / norm_c^2 — square the sqrt'd value, as JAX does
  float sf = __fdiv_rn(__fmul_rn(nrm, nrm), __fmul_rn(nc, nc));
  float scale = __fadd_rn(1.0f, __fmul_rn(sf, 25.0f));
  float x0 = __fmul_rn(c0, scale);
  float x1 = __fmul_rn(c1, scale);
  float x2 = __fmul_rn(c2, scale);
  bool m = (x0 >= -50.0f) && (x0 <= 150.0f) &&
           (x1 >= -50.0f) && (x1 <= 50.0f) &&
           (x2 >= -1.0f) && (x2 <= 3.0f);
  centers[j] = x0;
  centers[R3 + j] = x1;
  centers[2 * R3 + j] = x2;
  mask[j] = m ? 1.0f : 0.0f;
}

extern "C" void kernel_launch(void* const* d_in, const int* in_sizes, int n_in,
                              void* d_out, int out_size, void* d_ws, size_t ws_size,
                              hipStream_t stream) {
  const float4* pts = (const float4*)d_in[0];
  int n = in_sizes[0] / 4;               // 4,000,000 points, [N,4] layout
  float* out = (float*)d_out;
  float* coors = out;                    // 3*N floats
  float* centers = out + (size_t)3 * n;  // 3*R^3 floats
  float* cmask = centers + (size_t)3 * R3;

  voxelize_kernel<<<(n + 255) / 256, 256, 0, stream>>>(pts, coors, n);
  centers_kernel<<<(R3 + 255) / 256, 256, 0, stream>>>(centers, cmask);
}